// Round 14
// baseline (109.890 us; speedup 1.0000x reference)
//
#include <hip/hip_runtime.h>
#include <math.h>

// ---------------------------------------------------------------------------
// KAN-Conv CIFAR net on gfx950, round 19.
// Ledger: dur = kernels(~37us) + ~40us ws-poison fill (fixed) + ~28us launch
// overhead. r18's ILP edits were null -> kernel B is phase/barrier-bound at
// 1 block/CU (all pipes <30%). This round: split B into 2 blocks/image
// (grid 512, 2 blocks/CU) so two blocks' phases overlap per CU:
//  - block h stages h1 rows 6h-1..6h+10 (halo recompute, +25% L2 MFMA, free
//    at 3.6% MfmaUtil), computes L2 pooled rows {0..4 | 3..7} (waves 0..4),
//    stages act3 [16][6][10] from its own h2 slice, L3 pooled rows {0,1|2,3}
//    with 8-wave K-split (pairs do 18 steps, LDS partial reduce), then
//    PARTIAL linear over its 256-elem h3 half -> atomicAdd into out
//    (h=0 adds bias; kernel A zeroes out each launch -> replay-safe).
//  - LDS 46080B -> 2 blocks/CU; launch_bounds(512,4) caps VGPR 128 (largest
//    live array bfr3[18]=72).
// Kernel A: r16-verbatim L1 + w3g prep + out zeroing (blocks 16..65).
// ---------------------------------------------------------------------------

#define BATCH 256

typedef short bf16x8 __attribute__((ext_vector_type(8)));
typedef float f32x4  __attribute__((ext_vector_type(4)));

__device__ __forceinline__ unsigned f2bf(float f) {
    unsigned u = __float_as_uint(f);
    u += 0x7fffu + ((u >> 16) & 1u);       // round-to-nearest-even
    return u >> 16;
}
__device__ __forceinline__ unsigned pk2(float a, float b) {
    return f2bf(a) | (f2bf(b) << 16);
}

__device__ __forceinline__ void bspline_basis(float x, float bs[6]) {
    const float h = 2.0f / 3.0f;
    float g[10];
#pragma unroll
    for (int i = 0; i < 10; ++i) g[i] = (float)(i - 3) * h - 1.0f;
    float b[9];
#pragma unroll
    for (int i = 0; i < 9; ++i) b[i] = (x >= g[i] && x < g[i + 1]) ? 1.0f : 0.0f;
#pragma unroll
    for (int j = 1; j <= 3; ++j) {
        const float inv_d = 1.0f / ((float)j * h);
#pragma unroll
        for (int i = 0; i + j < 9; ++i) {
            float left  = (x - g[i]) * inv_d;
            float right = (g[i + j + 1] - x) * inv_d;
            b[i] = left * b[i] + right * b[i + 1];
        }
    }
#pragma unroll
    for (int i = 0; i < 6; ++i) bs[i] = b[i];
}

// [silu, b0..b5, 0] as 8 bf16 in one uint4.
__device__ __forceinline__ uint4 act_record(float val) {
    float silu = val / (1.0f + __expf(-val));
    float bs[6];
    bspline_basis(val, bs);
    uint4 r;
    r.x = pk2(silu, bs[0]);
    r.y = pk2(bs[1], bs[2]);
    r.z = pk2(bs[3], bs[4]);
    r.w = f2bf(bs[5]);
    return r;
}

__device__ __forceinline__ uint4 fuse_w(const float* bw, const float* sw,
                                        const float* sc, int j) {
    float s = sc[j];
    uint4 r;
    r.x = pk2(bw[j],             sw[j * 6 + 0] * s);
    r.y = pk2(sw[j * 6 + 1] * s, sw[j * 6 + 2] * s);
    r.z = pk2(sw[j * 6 + 3] * s, sw[j * 6 + 4] * s);
    r.w = f2bf(sw[j * 6 + 5] * s);
    return r;
}

// ---------------------------------------------------------------------------
// Kernel A: L1 conv+pool (r15-verbatim) + w3g prep + out zeroing.
// grid 512 (img x vhalf) x 512 threads, 2 blocks/CU.
// ---------------------------------------------------------------------------
__global__ __launch_bounds__(512, 4) void kan_l1(
        const float* __restrict__ x,
        const float* __restrict__ bw, const float* __restrict__ sw,
        const float* __restrict__ sc,
        const float* __restrict__ bw3, const float* __restrict__ sw3,
        const float* __restrict__ sc3,
        uint4* __restrict__ w3g,
        float* __restrict__ lin_out,
        float* __restrict__ out) {
    constexpr int C = 3, H = 32, W = 32, F = 27, FP = 28, NS = 7;
    constexpr int RT = 18, TC = 34, NT = 512;

    __shared__ uint4 s_act[C * RT * TC];           // 1836 recs = 29.4KB
    __shared__ uint4 s_w[FP * 16];                 // 7.2KB

    const int tid = threadIdx.x;
    const int bid = blockIdx.x;
    const int b   = bid >> 1;
    const int v   = bid & 1;

    // ---- prep w3g (blocks 0..8): [tap][32] bf16x8
    if (bid < 9) {
        int i = bid * NT + tid;
        if (i < 4608) {
            int o = i / 144, fp = i % 144;
            w3g[fp * 32 + o] = fuse_w(bw3, sw3, sc3, i);
        }
    }
    // ---- zero out (blocks 16..65) for kernel B's atomicAdd
    if (bid >= 16 && bid < 66) {
        int i = (bid - 16) * NT + tid;
        if (i < BATCH * 100) lin_out[i] = 0.0f;
    }

    // ---- stage own weights [fp][16] (zeros for pad tap / o>=8)
    for (int i = tid; i < FP * 16; i += NT) {
        int fp = i >> 4, o = i & 15;
        uint4 r = make_uint4(0u, 0u, 0u, 0u);
        if (fp < F && o < 8) r = fuse_w(bw, sw, sc, o * F + fp);
        s_w[i] = r;
    }

    // ---- stage act records
    const int r0 = 16 * v - 1;
    const float* xb = x + (size_t)b * C * H * W;
    for (int i = tid; i < C * RT * TC; i += NT) {
        int cc  = i / (RT * TC);
        int rr  = (i / TC) % RT;
        int col = i % TC;
        int gr = r0 + rr, gc = col - 1;
        float val = 0.0f;
        if ((unsigned)gr < (unsigned)H && (unsigned)gc < (unsigned)W)
            val = xb[(cc * H + gr) * W + gc];
        s_act[i] = act_record(val);
    }
    __syncthreads();

    const int lane = tid & 63;
    const int wv   = tid >> 6;
    const int kg   = lane >> 4;
    const int oc   = lane & 15;
    const int m    = lane & 15;

    bf16x8 bfr[NS];
#pragma unroll
    for (int s = 0; s < NS; ++s)
        bfr[s] = *reinterpret_cast<const bf16x8*>(&s_w[(4 * s + kg) * 16 + oc]);

    int pixoff[4];
#pragma unroll
    for (int t = 0; t < 4; ++t)
        pixoff[t] = (2 * wv + (t >> 1)) * TC + 16 * (t & 1) + m;

    f32x4 acc[4];
#pragma unroll
    for (int t = 0; t < 4; ++t) acc[t] = (f32x4){0.f, 0.f, 0.f, 0.f};

#pragma unroll
    for (int s = 0; s < NS; ++s) {
        int tp = 4 * s + kg;
        tp = (tp > F - 1) ? F - 1 : tp;            // pad tap: B=0 anyway
        int c  = tp / 9;
        int t9 = tp - 9 * c;
        int ky = t9 / 3;
        int kx = t9 - 3 * ky;
        int base = (c * RT + ky) * TC + kx;
#pragma unroll
        for (int t = 0; t < 4; ++t) {
            bf16x8 a = *reinterpret_cast<const bf16x8*>(&s_act[base + pixoff[t]]);
            acc[t] = __builtin_amdgcn_mfma_f32_16x16x32_bf16(a, bfr[s], acc[t], 0, 0, 0);
        }
    }

    if (oc < 8) {
        f32x4 e0, e1;
#pragma unroll
        for (int p = 0; p < 4; ++p) {
            e0[p] = fmaxf(acc[0][p], acc[2][p]);
            e1[p] = fmaxf(acc[1][p], acc[3][p]);
        }
        float* op = out + (((size_t)b * 8 + oc) * 16 + (8 * v + wv)) * 16;
        op[2 * kg]         = fmaxf(e0[0], e0[1]);
        op[2 * kg + 1]     = fmaxf(e0[2], e0[3]);
        op[8 + 2 * kg]     = fmaxf(e1[0], e1[1]);
        op[8 + 2 * kg + 1] = fmaxf(e1[2], e1[3]);
    }
}

// ---------------------------------------------------------------------------
// Kernel B: per-image-HALF L2 -> L3 -> partial linear. grid 512 (img x half)
// x 512 threads, 2 blocks/CU.  LDS arena (46080 B):
//   P1: act2[1728]u4 @0..27647 | w2[1152]u4 @27648..46079
//   P2: h2[1024]f @0..4095 | act3[960]u4 @4096..19455 | part[256]f4 @19456..23551
//   P3: h3[512]f @0..2047
// ---------------------------------------------------------------------------
__global__ __launch_bounds__(512, 4) void kan_l2l3lin(
        const float* __restrict__ h1,
        const float* __restrict__ bw2, const float* __restrict__ sw2,
        const float* __restrict__ sc2,
        const uint4* __restrict__ w3g,
        const float* __restrict__ lin_w, const float* __restrict__ lin_b,
        float* __restrict__ out) {
    constexpr int NT = 512;
    __shared__ alignas(16) unsigned char s_mem[46080];
    uint4* s_act2 = (uint4*)s_mem;                 // [1728]
    uint4* s_w2   = (uint4*)(s_mem + 27648);       // [1152]
    float* s_h2   = (float*)s_mem;                 // [1024]
    uint4* s_act3 = (uint4*)(s_mem + 4096);        // [960]
    f32x4* s_part = (f32x4*)(s_mem + 19456);       // [256]
    float* s_h3   = (float*)s_mem;                 // [512]

    const int tid = threadIdx.x;
    const int bid = blockIdx.x;
    const int n   = bid >> 1;
    const int hh  = bid & 1;                       // image half (vertical)
    const int lane = tid & 63;
    const int wv   = tid >> 6;
    const int kg   = lane >> 4;
    const int oc   = lane & 15;
    const int m    = lane & 15;

    // ---- P1 stage: w2 fused [fp][16]
    for (int i = tid; i < 72 * 16; i += NT) {
        int fp = i >> 4, o = i & 15;
        s_w2[i] = fuse_w(bw2, sw2, sc2, o * 72 + fp);
    }
    // ---- P1 stage: act2 from h1 (8ch x 12 x 18; h1 rows 6hh-1 .. 6hh+10)
    const float* xb = h1 + (size_t)n * 8 * 16 * 16;
    for (int i = tid; i < 1728; i += NT) {
        int cc  = i / 216;
        int rr  = (i / 18) % 12;
        int col = i % 18;
        int gr = 6 * hh - 1 + rr, gc = col - 1;
        float val = 0.0f;
        if ((unsigned)gr < 16u && (unsigned)gc < 16u)
            val = xb[(cc * 16 + gr) * 16 + gc];
        s_act2[i] = act_record(val);
    }
    __syncthreads();

    // ---- L2 MFMA: waves 0..4, pooled row prow = 3hh + wv (K split 9+9)
    float e0 = 0.f, e1 = 0.f, e2 = 0.f, e3 = 0.f;
    if (wv < 5) {
        bf16x8 bfr2[18];
#pragma unroll
        for (int s = 0; s < 18; ++s)
            bfr2[s] = *reinterpret_cast<const bf16x8*>(&s_w2[(4 * s + kg) * 16 + oc]);
        const int p0 = (2 * wv) * 18 + m;          // local conv rows 2wv, 2wv+1
        const int p1 = p0 + 18;
        f32x4 a0 = (f32x4){0.f, 0.f, 0.f, 0.f}, a1 = a0, b0 = a0, b1 = a0;
#pragma unroll
        for (int s = 0; s < 18; ++s) {
            int tp = 4 * s + kg;
            int c  = tp / 9;
            int t9 = tp - 9 * c;
            int ky = t9 / 3;
            int kx = t9 - 3 * ky;
            int base = c * 216 + ky * 18 + kx;
            bf16x8 av0 = *reinterpret_cast<const bf16x8*>(&s_act2[base + p0]);
            bf16x8 av1 = *reinterpret_cast<const bf16x8*>(&s_act2[base + p1]);
            if (s < 9) {
                a0 = __builtin_amdgcn_mfma_f32_16x16x32_bf16(av0, bfr2[s], a0, 0, 0, 0);
                a1 = __builtin_amdgcn_mfma_f32_16x16x32_bf16(av1, bfr2[s], a1, 0, 0, 0);
            } else {
                b0 = __builtin_amdgcn_mfma_f32_16x16x32_bf16(av0, bfr2[s], b0, 0, 0, 0);
                b1 = __builtin_amdgcn_mfma_f32_16x16x32_bf16(av1, bfr2[s], b1, 0, 0, 0);
            }
        }
        a0 = a0 + b0;
        a1 = a1 + b1;
        e0 = fmaxf(a0[0], a1[0]);
        e1 = fmaxf(a0[1], a1[1]);
        e2 = fmaxf(a0[2], a1[2]);
        e3 = fmaxf(a0[3], a1[3]);
    }
    __syncthreads();                               // act2/w2 reads done
    if (wv < 5) {
        const int prow = 3 * hh + wv;              // global pooled row
        s_h2[(oc * 8 + prow) * 8 + 2 * kg]     = fmaxf(e0, e1);
        s_h2[(oc * 8 + prow) * 8 + 2 * kg + 1] = fmaxf(e2, e3);
    }
    __syncthreads();

    // ---- P2 stage: act3 [16ch][6][10] from h2 rows 4hh-1 .. 4hh+4
    for (int i = tid; i < 960; i += NT) {
        int cc  = i / 60;
        int lr  = (i / 10) % 6;
        int col = i % 10;
        int hr = 4 * hh - 1 + lr, gc = col - 1;
        float val = 0.0f;
        if ((unsigned)hr < 8u && (unsigned)gc < 8u)
            val = s_h2[(cc * 8 + hr) * 8 + gc];
        s_act3[i] = act_record(val);
    }
    __syncthreads();

    // ---- L3 MFMA: 4 tasks (mt_l x o03) x 2 K-halves across 8 waves
    {
        const int mt_l = wv & 1;                   // local pooled row 0/1
        const int o03  = 16 * ((wv >> 1) & 1);     // o-half
        const int kh   = wv >> 2;                  // K-half
        bf16x8 bfr3[18];
#pragma unroll
        for (int s = 0; s < 18; ++s)
            bfr3[s] = *reinterpret_cast<const bf16x8*>(
                &w3g[(4 * (s + 18 * kh) + kg) * 32 + o03 + oc]);
        const int poff = (2 * mt_l + (m >> 3)) * 10 + (m & 7);
        f32x4 a3 = (f32x4){0.f, 0.f, 0.f, 0.f}, a3b = a3;
#pragma unroll
        for (int s = 0; s < 18; ++s) {
            int tp = 4 * (s + 18 * kh) + kg;
            int c  = tp / 9;
            int t9 = tp - 9 * c;
            int ky = t9 / 3;
            int kx = t9 - 3 * ky;
            int base = (c * 6 + ky) * 10 + kx;
            bf16x8 av = *reinterpret_cast<const bf16x8*>(&s_act3[base + poff]);
            if (s < 9)
                a3 = __builtin_amdgcn_mfma_f32_16x16x32_bf16(av, bfr3[s], a3, 0, 0, 0);
            else
                a3b = __builtin_amdgcn_mfma_f32_16x16x32_bf16(av, bfr3[s], a3b, 0, 0, 0);
        }
        a3 = a3 + a3b;
        if (kh == 1) s_part[(wv - 4) * 64 + lane] = a3;
        __syncthreads();
        if (kh == 0) {
            f32x4 t = s_part[wv * 64 + lane];
            a3 = a3 + t;
            float q0 = fmaxf(a3[0], a3[1]);
            float q1 = fmaxf(a3[2], a3[3]);
            float y0 = fmaxf(q0, __shfl_xor(q0, 32));
            float y1 = fmaxf(q1, __shfl_xor(q1, 32));
            const int mtg = 2 * hh + mt_l;         // global pooled row
            if (kg < 2) {
                s_h3[(o03 + oc) * 16 + mtg * 4 + 2 * kg]     = y0;
                s_h3[(o03 + oc) * 16 + mtg * 4 + 2 * kg + 1] = y1;
            }
        }
    }
    __syncthreads();

    // ---- partial linear over this block's 256-elem h3 half; atomicAdd out
    {
        const float4* hf = (const float4*)s_h3;
        const int fidx = (lane >> 1) * 4 + 2 * hh + (lane & 1);
        const float4 hv = hf[fidx];
#pragma unroll 1
        for (int o = wv; o < 100; o += 8) {
            const float4 w0 = ((const float4*)(lin_w + (size_t)o * 512))[fidx];
            float p = w0.x * hv.x + w0.y * hv.y + w0.z * hv.z + w0.w * hv.w;
            p += __shfl_xor(p, 32);
            p += __shfl_xor(p, 16);
            p += __shfl_xor(p, 8);
            p += __shfl_xor(p, 4);
            p += __shfl_xor(p, 2);
            p += __shfl_xor(p, 1);
            if (lane == 0)
                atomicAdd(&out[(size_t)n * 100 + o],
                          p + (hh == 0 ? lin_b[o] : 0.0f));
        }
    }
}

extern "C" void kernel_launch(void* const* d_in, const int* in_sizes, int n_in,
                              void* d_out, int out_size, void* d_ws, size_t ws_size,
                              hipStream_t stream) {
    const float* x     = (const float*)d_in[0];
    const float* c1_bw = (const float*)d_in[1];
    const float* c1_sw = (const float*)d_in[2];
    const float* c1_sc = (const float*)d_in[3];
    const float* c2_bw = (const float*)d_in[4];
    const float* c2_sw = (const float*)d_in[5];
    const float* c2_sc = (const float*)d_in[6];
    const float* c3_bw = (const float*)d_in[7];
    const float* c3_sw = (const float*)d_in[8];
    const float* c3_sc = (const float*)d_in[9];
    const float* lin_w = (const float*)d_in[10];
    const float* lin_b = (const float*)d_in[11];
    float* out = (float*)d_out;

    float* ws = (float*)d_ws;
    float* h1 = ws;                      // 256*8*16*16 = 524288 floats
    uint4* w3g = (uint4*)(h1 + 524288);  // 4608 records = 73728 B

    // Kernel A: L1 -> h1; + w3g prep (blocks 0-8) + out zeroing (blocks 16-65).
    kan_l1<<<512, 512, 0, stream>>>(x, c1_bw, c1_sw, c1_sc,
                                    c3_bw, c3_sw, c3_sc, w3g, out, h1);
    // Kernel B: per-image-half L2 -> L3 -> partial linear. 512 blocks x 512.
    kan_l2l3lin<<<512, 512, 0, stream>>>(h1, c2_bw, c2_sw, c2_sc,
                                         w3g, lin_w, lin_b, out);
}

// Round 15
// 101.589 us; speedup vs baseline: 1.0817x; 1.0817x over previous
//
#include <hip/hip_runtime.h>
#include <math.h>

// ---------------------------------------------------------------------------
// KAN-Conv CIFAR net on gfx950, round 20.
// Ledger: dur = kernels(~37us GPU) + ~68us fixed (ws-poison fill + launch).
// r17/r18/r19 all failed to restructure kernel B -> it is staging-VALU-bound:
// bspline_basis (Cox-de-Boor, ~150 ops) x 1.1M records dominates (r17 PMC:
// VALUBusy 28% vs MfmaUtil 3.6%). This round, ONE isolated change vs r18:
// closed-form uniform-grid cubic B-spline (4 active bases, standard blending
// weights, selects for the 6-entry truncation) ~70 ops, 2.3x cheaper.
// Identical math up to last-ulp at cell boundaries (bf16 swallows it).
// ---------------------------------------------------------------------------

#define BATCH 256

typedef short bf16x8 __attribute__((ext_vector_type(8)));
typedef float f32x4  __attribute__((ext_vector_type(4)));

__device__ __forceinline__ unsigned f2bf(float f) {
    unsigned u = __float_as_uint(f);
    u += 0x7fffu + ((u >> 16) & 1u);       // round-to-nearest-even
    return u >> 16;
}
__device__ __forceinline__ unsigned pk2(float a, float b) {
    return f2bf(a) | (f2bf(b) << 16);
}

// Closed-form cubic B-spline on the uniform extended grid g[i]=(i-3)*(2/3)-1.
// x in cell c (c=0..8, c=floor((x+3)*1.5)): active bases c-3..c with the
// standard uniform blending weights; outputs truncated to bs[0..5]; x outside
// [-3,3) -> all zero (matches reference recursion).
__device__ __forceinline__ void bspline_basis(float x, float bs[6]) {
    float s  = (x + 3.0f) * 1.5f;
    float cf = floorf(s);
    float t  = s - cf;
    int  ci  = (int)cf;
    float t2 = t * t, t3 = t2 * t;
    float omt = 1.0f - t;
    const float k6 = 1.0f / 6.0f;
    float w0 = omt * omt * omt * k6;
    float w1 = (3.0f * t3 - 6.0f * t2 + 4.0f) * k6;
    float w2 = (-3.0f * t3 + 3.0f * t2 + 3.0f * t + 1.0f) * k6;
    float w3 = t3 * k6;
#pragma unroll
    for (int i = 0; i < 6; ++i) {
        int j = i - ci + 3;                // which of the 4 weights lands here
        float v = 0.0f;
        v = (j == 0) ? w0 : v;
        v = (j == 1) ? w1 : v;
        v = (j == 2) ? w2 : v;
        v = (j == 3) ? w3 : v;
        bs[i] = v;
    }
}

// [silu, b0..b5, 0] as 8 bf16 in one uint4.
__device__ __forceinline__ uint4 act_record(float val) {
    float silu = val / (1.0f + __expf(-val));
    float bs[6];
    bspline_basis(val, bs);
    uint4 r;
    r.x = pk2(silu, bs[0]);
    r.y = pk2(bs[1], bs[2]);
    r.z = pk2(bs[3], bs[4]);
    r.w = f2bf(bs[5]);
    return r;
}

__device__ __forceinline__ uint4 fuse_w(const float* bw, const float* sw,
                                        const float* sc, int j) {
    float s = sc[j];
    uint4 r;
    r.x = pk2(bw[j],             sw[j * 6 + 0] * s);
    r.y = pk2(sw[j * 6 + 1] * s, sw[j * 6 + 2] * s);
    r.z = pk2(sw[j * 6 + 3] * s, sw[j * 6 + 4] * s);
    r.w = f2bf(sw[j * 6 + 5] * s);
    return r;
}

// ---------------------------------------------------------------------------
// Kernel A: L1 conv+pool (r15-verbatim) + prep of L3 bf16 weight table w3g.
// grid 512 (img x vhalf) x 512 threads, 2 blocks/CU.
// ---------------------------------------------------------------------------
__global__ __launch_bounds__(512, 4) void kan_l1(
        const float* __restrict__ x,
        const float* __restrict__ bw, const float* __restrict__ sw,
        const float* __restrict__ sc,
        const float* __restrict__ bw3, const float* __restrict__ sw3,
        const float* __restrict__ sc3,
        uint4* __restrict__ w3g,
        float* __restrict__ out) {
    constexpr int C = 3, H = 32, W = 32, F = 27, FP = 28, NS = 7;
    constexpr int RT = 18, TC = 34, NT = 512;

    __shared__ uint4 s_act[C * RT * TC];           // 1836 recs = 29.4KB
    __shared__ uint4 s_w[FP * 16];                 // 7.2KB

    const int tid = threadIdx.x;
    const int bid = blockIdx.x;
    const int b   = bid >> 1;
    const int v   = bid & 1;

    // ---- prep w3g (blocks 0..8): [tap][32] bf16x8
    if (bid < 9) {
        int i = bid * NT + tid;
        if (i < 4608) {
            int o = i / 144, fp = i % 144;
            w3g[fp * 32 + o] = fuse_w(bw3, sw3, sc3, i);
        }
    }

    // ---- stage own weights [fp][16] (zeros for pad tap / o>=8)
    for (int i = tid; i < FP * 16; i += NT) {
        int fp = i >> 4, o = i & 15;
        uint4 r = make_uint4(0u, 0u, 0u, 0u);
        if (fp < F && o < 8) r = fuse_w(bw, sw, sc, o * F + fp);
        s_w[i] = r;
    }

    // ---- stage act records
    const int r0 = 16 * v - 1;
    const float* xb = x + (size_t)b * C * H * W;
    for (int i = tid; i < C * RT * TC; i += NT) {
        int cc  = i / (RT * TC);
        int rr  = (i / TC) % RT;
        int col = i % TC;
        int gr = r0 + rr, gc = col - 1;
        float val = 0.0f;
        if ((unsigned)gr < (unsigned)H && (unsigned)gc < (unsigned)W)
            val = xb[(cc * H + gr) * W + gc];
        s_act[i] = act_record(val);
    }
    __syncthreads();

    const int lane = tid & 63;
    const int wv   = tid >> 6;
    const int kg   = lane >> 4;
    const int oc   = lane & 15;
    const int m    = lane & 15;

    bf16x8 bfr[NS];
#pragma unroll
    for (int s = 0; s < NS; ++s)
        bfr[s] = *reinterpret_cast<const bf16x8*>(&s_w[(4 * s + kg) * 16 + oc]);

    int pixoff[4];
#pragma unroll
    for (int t = 0; t < 4; ++t)
        pixoff[t] = (2 * wv + (t >> 1)) * TC + 16 * (t & 1) + m;

    f32x4 acc[4];
#pragma unroll
    for (int t = 0; t < 4; ++t) acc[t] = (f32x4){0.f, 0.f, 0.f, 0.f};

#pragma unroll
    for (int s = 0; s < NS; ++s) {
        int tp = 4 * s + kg;
        tp = (tp > F - 1) ? F - 1 : tp;            // pad tap: B=0 anyway
        int c  = tp / 9;
        int t9 = tp - 9 * c;
        int ky = t9 / 3;
        int kx = t9 - 3 * ky;
        int base = (c * RT + ky) * TC + kx;
#pragma unroll
        for (int t = 0; t < 4; ++t) {
            bf16x8 a = *reinterpret_cast<const bf16x8*>(&s_act[base + pixoff[t]]);
            acc[t] = __builtin_amdgcn_mfma_f32_16x16x32_bf16(a, bfr[s], acc[t], 0, 0, 0);
        }
    }

    if (oc < 8) {
        f32x4 e0, e1;
#pragma unroll
        for (int p = 0; p < 4; ++p) {
            e0[p] = fmaxf(acc[0][p], acc[2][p]);
            e1[p] = fmaxf(acc[1][p], acc[3][p]);
        }
        float* op = out + (((size_t)b * 8 + oc) * 16 + (8 * v + wv)) * 16;
        op[2 * kg]         = fmaxf(e0[0], e0[1]);
        op[2 * kg + 1]     = fmaxf(e0[2], e0[3]);
        op[8 + 2 * kg]     = fmaxf(e1[0], e1[1]);
        op[8 + 2 * kg + 1] = fmaxf(e1[2], e1[3]);
    }
}

// ---------------------------------------------------------------------------
// Kernel B: L2 conv+pool -> L3 conv+pool -> linear, one block per image.
// grid 256 x 512 threads.  LDS arena phases:
//   P1: act2[2592]u4 (0..41471) | w2[1152]u4 (41472..59903)
//   P2: h2[1024]f   (0..4095)   | act3[1600]u4 (4096..29695)
//   P3: h3[512]f    (0..2047)
// ---------------------------------------------------------------------------
__global__ __launch_bounds__(512, 2) void kan_l2l3lin(
        const float* __restrict__ h1,
        const float* __restrict__ bw2, const float* __restrict__ sw2,
        const float* __restrict__ sc2,
        const uint4* __restrict__ w3g,
        const float* __restrict__ lin_w, const float* __restrict__ lin_b,
        float* __restrict__ out) {
    constexpr int NT = 512;
    __shared__ alignas(16) unsigned char s_mem[59904];
    uint4* s_act2 = (uint4*)s_mem;                 // [2592]
    uint4* s_w2   = (uint4*)(s_mem + 41472);       // [1152]
    float* s_h2   = (float*)s_mem;                 // [1024]
    uint4* s_act3 = (uint4*)(s_mem + 4096);        // [1600]
    float* s_h3   = (float*)s_mem;                 // [512]

    const int tid = threadIdx.x;
    const int n   = blockIdx.x;
    const int lane = tid & 63;
    const int wv   = tid >> 6;
    const int kg   = lane >> 4;
    const int oc   = lane & 15;
    const int m    = lane & 15;

    // ---- P1 stage: w2 fused [fp][16]
    for (int i = tid; i < 72 * 16; i += NT) {
        int fp = i >> 4, o = i & 15;
        s_w2[i] = fuse_w(bw2, sw2, sc2, o * 72 + fp);
    }
    // ---- P1 stage: act2 from h1 (8ch x 18 x 18, halo)
    const float* xb = h1 + (size_t)n * 8 * 16 * 16;
    for (int i = tid; i < 8 * 18 * 18; i += NT) {
        int cc  = i / 324;
        int rr  = (i / 18) % 18;
        int col = i % 18;
        int gr = rr - 1, gc = col - 1;
        float val = 0.0f;
        if ((unsigned)gr < 16u && (unsigned)gc < 16u)
            val = xb[(cc * 16 + gr) * 16 + gc];
        s_act2[i] = act_record(val);
    }
    __syncthreads();

    // ---- L2 MFMA (K split 9+9 for ILP): 2 row-tiles per wave
    {
        bf16x8 bfr2[18];
#pragma unroll
        for (int s = 0; s < 18; ++s)
            bfr2[s] = *reinterpret_cast<const bf16x8*>(&s_w2[(4 * s + kg) * 16 + oc]);
        const int p0 = (2 * wv) * 18 + m;
        const int p1 = p0 + 18;
        f32x4 a0 = (f32x4){0.f, 0.f, 0.f, 0.f}, a1 = a0, b0 = a0, b1 = a0;
#pragma unroll
        for (int s = 0; s < 18; ++s) {
            int tp = 4 * s + kg;
            int c  = tp / 9;
            int t9 = tp - 9 * c;
            int ky = t9 / 3;
            int kx = t9 - 3 * ky;
            int base = (c * 18 + ky) * 18 + kx;
            bf16x8 av0 = *reinterpret_cast<const bf16x8*>(&s_act2[base + p0]);
            bf16x8 av1 = *reinterpret_cast<const bf16x8*>(&s_act2[base + p1]);
            if (s < 9) {
                a0 = __builtin_amdgcn_mfma_f32_16x16x32_bf16(av0, bfr2[s], a0, 0, 0, 0);
                a1 = __builtin_amdgcn_mfma_f32_16x16x32_bf16(av1, bfr2[s], a1, 0, 0, 0);
            } else {
                b0 = __builtin_amdgcn_mfma_f32_16x16x32_bf16(av0, bfr2[s], b0, 0, 0, 0);
                b1 = __builtin_amdgcn_mfma_f32_16x16x32_bf16(av1, bfr2[s], b1, 0, 0, 0);
            }
        }
        a0 = a0 + b0;
        a1 = a1 + b1;
        float e0 = fmaxf(a0[0], a1[0]);
        float e1 = fmaxf(a0[1], a1[1]);
        float e2 = fmaxf(a0[2], a1[2]);
        float e3 = fmaxf(a0[3], a1[3]);
        __syncthreads();                           // act2/w2 reads done
        // pooled h2: ch=oc, prow=wv, pcols 2kg,2kg+1
        s_h2[(oc * 8 + wv) * 8 + 2 * kg]     = fmaxf(e0, e1);
        s_h2[(oc * 8 + wv) * 8 + 2 * kg + 1] = fmaxf(e2, e3);
    }
    __syncthreads();

    // ---- P2 stage: act3 from LDS h2 (16ch x 10 x 10, halo)
    for (int i = tid; i < 16 * 10 * 10; i += NT) {
        int cc  = i / 100;
        int rr  = (i / 10) % 10;
        int col = i % 10;
        int gr = rr - 1, gc = col - 1;
        float val = 0.0f;
        if ((unsigned)gr < 8u && (unsigned)gc < 8u)
            val = s_h2[(cc * 8 + gr) * 8 + gc];
        s_act3[i] = act_record(val);
    }
    __syncthreads();

    // ---- L3 MFMA (K split 18+18): wave wv -> mt=wv&3, o-half 16*(wv>>2)
    {
        const int mt  = wv & 3;
        const int o03 = 16 * (wv >> 2);
        bf16x8 bfr3[36];
#pragma unroll
        for (int s = 0; s < 36; ++s)
            bfr3[s] = *reinterpret_cast<const bf16x8*>(&w3g[(4 * s + kg) * 32 + o03 + oc]);
        const int poff = (2 * mt + (m >> 3)) * 10 + (m & 7);
        f32x4 a3 = (f32x4){0.f, 0.f, 0.f, 0.f}, a3b = a3;
#pragma unroll
        for (int s = 0; s < 36; ++s) {
            int tp = 4 * s + kg;
            int c  = tp / 9;
            int t9 = tp - 9 * c;
            int ky = t9 / 3;
            int kx = t9 - 3 * ky;
            int base = (c * 10 + ky) * 10 + kx;
            bf16x8 av = *reinterpret_cast<const bf16x8*>(&s_act3[base + poff]);
            if (s < 18)
                a3 = __builtin_amdgcn_mfma_f32_16x16x32_bf16(av, bfr3[s], a3, 0, 0, 0);
            else
                a3b = __builtin_amdgcn_mfma_f32_16x16x32_bf16(av, bfr3[s], a3b, 0, 0, 0);
        }
        a3 = a3 + a3b;
        float q0 = fmaxf(a3[0], a3[1]);
        float q1 = fmaxf(a3[2], a3[3]);
        float y0 = fmaxf(q0, __shfl_xor(q0, 32));
        float y1 = fmaxf(q1, __shfl_xor(q1, 32));
        // h3 (bytes 0..2047) disjoint from act3 (4096+): no pre-sync needed
        if (kg < 2) {
            s_h3[(o03 + oc) * 16 + mt * 4 + 2 * kg]     = y0;
            s_h3[(o03 + oc) * 16 + mt * 4 + 2 * kg + 1] = y1;
        }
    }
    __syncthreads();

    // ---- linear: 2-deep pipelined w-row loads + shfl reduce
    {
        const float4* hf = (const float4*)s_h3;
        const float4 h0v = hf[lane];
        const float4 h1v = hf[lane + 64];
        const float4* wr = (const float4*)(lin_w + (size_t)wv * 512);
        float4 w0 = wr[lane];
        float4 w1 = wr[lane + 64];
#pragma unroll 1
        for (int o = wv; o < 100; o += 8) {
            float4 nw0, nw1;
            const int on = o + 8;
            if (on < 100) {
                const float4* wn = (const float4*)(lin_w + (size_t)on * 512);
                nw0 = wn[lane];
                nw1 = wn[lane + 64];
            }
            float p = w0.x * h0v.x + w0.y * h0v.y + w0.z * h0v.z + w0.w * h0v.w
                    + w1.x * h1v.x + w1.y * h1v.y + w1.z * h1v.z + w1.w * h1v.w;
            p += __shfl_xor(p, 32);
            p += __shfl_xor(p, 16);
            p += __shfl_xor(p, 8);
            p += __shfl_xor(p, 4);
            p += __shfl_xor(p, 2);
            p += __shfl_xor(p, 1);
            if (lane == 0) out[(size_t)n * 100 + o] = p + lin_b[o];
            w0 = nw0;
            w1 = nw1;
        }
    }
}

extern "C" void kernel_launch(void* const* d_in, const int* in_sizes, int n_in,
                              void* d_out, int out_size, void* d_ws, size_t ws_size,
                              hipStream_t stream) {
    const float* x     = (const float*)d_in[0];
    const float* c1_bw = (const float*)d_in[1];
    const float* c1_sw = (const float*)d_in[2];
    const float* c1_sc = (const float*)d_in[3];
    const float* c2_bw = (const float*)d_in[4];
    const float* c2_sw = (const float*)d_in[5];
    const float* c2_sc = (const float*)d_in[6];
    const float* c3_bw = (const float*)d_in[7];
    const float* c3_sw = (const float*)d_in[8];
    const float* c3_sc = (const float*)d_in[9];
    const float* lin_w = (const float*)d_in[10];
    const float* lin_b = (const float*)d_in[11];
    float* out = (float*)d_out;

    float* ws = (float*)d_ws;
    float* h1 = ws;                      // 256*8*16*16 = 524288 floats
    uint4* w3g = (uint4*)(h1 + 524288);  // 4608 records = 73728 B

    // Kernel A: L1 [256,3,32,32] -> h1 [256,8,16,16]; + w3g prep (blocks 0-8).
    kan_l1<<<512, 512, 0, stream>>>(x, c1_bw, c1_sw, c1_sc,
                                    c3_bw, c3_sw, c3_sc, w3g, h1);
    // Kernel B: per-image L2 -> L3 -> linear. 256 blocks x 512.
    kan_l2l3lin<<<256, 512, 0, stream>>>(h1, c2_bw, c2_sw, c2_sc,
                                         w3g, lin_w, lin_b, out);
}

// Round 16
// 98.910 us; speedup vs baseline: 1.1110x; 1.0271x over previous
//
#include <hip/hip_runtime.h>
#include <hip/hip_bf16.h>
#include <math.h>

// ---------------------------------------------------------------------------
// KAN-Conv CIFAR net on gfx950, round 21.
// r20 (closed-form bspline) = 101.6us. Ledger: ~68us fixed (40 ws-poison
// fill + ~28 graph/launch), kernels ~33us, staging-VALU still the biggest
// kernel term. Two isolated changes vs r20:
//  (1) padding split: out-of-range pixels all produce the SAME record
//      act_record(0) -> prefill tiles with zrec (pure LDS stores), then an
//      interior-only loop with NO bounds checks and contiguous/float4 loads.
//      Skips full compute for 11%/21%/36% of act1/act2/act3 records.
//  (2) native bf16 pack: __float22bfloat162_rn pairs (compiler emits
//      v_cvt_pk_bf16_f32; RNE-identical to the old bit-trick) + __fdividef
//      in silu.
// MFMA bodies, kernel structure, LDS phasing: r20-verbatim (+2 barriers).
// ---------------------------------------------------------------------------

#define BATCH 256

typedef short bf16x8 __attribute__((ext_vector_type(8)));
typedef float f32x4  __attribute__((ext_vector_type(4)));

__device__ __forceinline__ unsigned pk2(float a, float b) {
    __hip_bfloat162 h = __float22bfloat162_rn(make_float2(a, b));
    unsigned u;
    __builtin_memcpy(&u, &h, 4);
    return u;
}
__device__ __forceinline__ unsigned f2bf(float f) {
    __hip_bfloat16 h = __float2bfloat16(f);
    unsigned short us;
    __builtin_memcpy(&us, &h, 2);
    return (unsigned)us;
}

// Closed-form cubic B-spline on the uniform extended grid g[i]=(i-3)*(2/3)-1.
__device__ __forceinline__ void bspline_basis(float x, float bs[6]) {
    float s  = (x + 3.0f) * 1.5f;
    float cf = floorf(s);
    float t  = s - cf;
    int  ci  = (int)cf;
    float t2 = t * t, t3 = t2 * t;
    float omt = 1.0f - t;
    const float k6 = 1.0f / 6.0f;
    float w0 = omt * omt * omt * k6;
    float w1 = (3.0f * t3 - 6.0f * t2 + 4.0f) * k6;
    float w2 = (-3.0f * t3 + 3.0f * t2 + 3.0f * t + 1.0f) * k6;
    float w3 = t3 * k6;
#pragma unroll
    for (int i = 0; i < 6; ++i) {
        int j = i - ci + 3;                // which of the 4 weights lands here
        float v = 0.0f;
        v = (j == 0) ? w0 : v;
        v = (j == 1) ? w1 : v;
        v = (j == 2) ? w2 : v;
        v = (j == 3) ? w3 : v;
        bs[i] = v;
    }
}

// [silu, b0..b5, 0] as 8 bf16 in one uint4.
__device__ __forceinline__ uint4 act_record(float val) {
    float silu = __fdividef(val, 1.0f + __expf(-val));
    float bs[6];
    bspline_basis(val, bs);
    uint4 r;
    r.x = pk2(silu, bs[0]);
    r.y = pk2(bs[1], bs[2]);
    r.z = pk2(bs[3], bs[4]);
    r.w = f2bf(bs[5]);
    return r;
}

__device__ __forceinline__ uint4 fuse_w(const float* bw, const float* sw,
                                        const float* sc, int j) {
    float s = sc[j];
    uint4 r;
    r.x = pk2(bw[j],             sw[j * 6 + 0] * s);
    r.y = pk2(sw[j * 6 + 1] * s, sw[j * 6 + 2] * s);
    r.z = pk2(sw[j * 6 + 3] * s, sw[j * 6 + 4] * s);
    r.w = f2bf(sw[j * 6 + 5] * s);
    return r;
}

// ---------------------------------------------------------------------------
// Kernel A: L1 conv+pool + prep of L3 bf16 weight table w3g.
// grid 512 (img x vhalf) x 512 threads, 2 blocks/CU.
// ---------------------------------------------------------------------------
__global__ __launch_bounds__(512, 4) void kan_l1(
        const float* __restrict__ x,
        const float* __restrict__ bw, const float* __restrict__ sw,
        const float* __restrict__ sc,
        const float* __restrict__ bw3, const float* __restrict__ sw3,
        const float* __restrict__ sc3,
        uint4* __restrict__ w3g,
        float* __restrict__ out) {
    constexpr int C = 3, F = 27, FP = 28, NS = 7;
    constexpr int RT = 18, TC = 34, NT = 512;

    __shared__ uint4 s_act[C * RT * TC];           // 1836 recs = 29.4KB
    __shared__ uint4 s_w[FP * 16];                 // 7.2KB

    const int tid = threadIdx.x;
    const int bid = blockIdx.x;
    const int b   = bid >> 1;
    const int v   = bid & 1;

    // ---- prep w3g (blocks 0..8): [tap][32] bf16x8
    if (bid < 9) {
        int i = bid * NT + tid;
        if (i < 4608) {
            int o = i / 144, fp = i % 144;
            w3g[fp * 32 + o] = fuse_w(bw3, sw3, sc3, i);
        }
    }

    // ---- stage own weights [fp][16] (zeros for pad tap / o>=8)
    for (int i = tid; i < FP * 16; i += NT) {
        int fp = i >> 4, o = i & 15;
        uint4 r = make_uint4(0u, 0u, 0u, 0u);
        if (fp < F && o < 8) r = fuse_w(bw, sw, sc, o * F + fp);
        s_w[i] = r;
    }

    // ---- stage acts: zrec prefill, then interior-only (17 rows x 32 cols/ch)
    const uint4 zrec = act_record(0.0f);
    for (int i = tid; i < C * RT * TC; i += NT) s_act[i] = zrec;
    __syncthreads();
    const float* xb = x + (size_t)b * C * 32 * 32;
    if (tid < 408) {                       // 3ch x 17 rows x 8 float4s
        int cc  = tid / 136;
        int rem = tid - cc * 136;
        int rr_i = rem >> 3;
        int c4   = (rem & 7) * 4;
        float4 v4 = *(const float4*)&xb[(cc * 32 + rr_i + 15 * v) * 32 + c4];
        uint4* dst = &s_act[(cc * RT + rr_i + 1 - v) * TC + c4 + 1];
        dst[0] = act_record(v4.x);
        dst[1] = act_record(v4.y);
        dst[2] = act_record(v4.z);
        dst[3] = act_record(v4.w);
    }
    __syncthreads();

    const int lane = tid & 63;
    const int wv   = tid >> 6;
    const int kg   = lane >> 4;
    const int oc   = lane & 15;
    const int m    = lane & 15;

    bf16x8 bfr[NS];
#pragma unroll
    for (int s = 0; s < NS; ++s)
        bfr[s] = *reinterpret_cast<const bf16x8*>(&s_w[(4 * s + kg) * 16 + oc]);

    int pixoff[4];
#pragma unroll
    for (int t = 0; t < 4; ++t)
        pixoff[t] = (2 * wv + (t >> 1)) * TC + 16 * (t & 1) + m;

    f32x4 acc[4];
#pragma unroll
    for (int t = 0; t < 4; ++t) acc[t] = (f32x4){0.f, 0.f, 0.f, 0.f};

#pragma unroll
    for (int s = 0; s < NS; ++s) {
        int tp = 4 * s + kg;
        tp = (tp > F - 1) ? F - 1 : tp;            // pad tap: B=0 anyway
        int c  = tp / 9;
        int t9 = tp - 9 * c;
        int ky = t9 / 3;
        int kx = t9 - 3 * ky;
        int base = (c * RT + ky) * TC + kx;
#pragma unroll
        for (int t = 0; t < 4; ++t) {
            bf16x8 a = *reinterpret_cast<const bf16x8*>(&s_act[base + pixoff[t]]);
            acc[t] = __builtin_amdgcn_mfma_f32_16x16x32_bf16(a, bfr[s], acc[t], 0, 0, 0);
        }
    }

    if (oc < 8) {
        f32x4 e0, e1;
#pragma unroll
        for (int p = 0; p < 4; ++p) {
            e0[p] = fmaxf(acc[0][p], acc[2][p]);
            e1[p] = fmaxf(acc[1][p], acc[3][p]);
        }
        float* op = out + (((size_t)b * 8 + oc) * 16 + (8 * v + wv)) * 16;
        op[2 * kg]         = fmaxf(e0[0], e0[1]);
        op[2 * kg + 1]     = fmaxf(e0[2], e0[3]);
        op[8 + 2 * kg]     = fmaxf(e1[0], e1[1]);
        op[8 + 2 * kg + 1] = fmaxf(e1[2], e1[3]);
    }
}

// ---------------------------------------------------------------------------
// Kernel B: L2 conv+pool -> L3 conv+pool -> linear, one block per image.
// grid 256 x 512 threads.  LDS arena phases:
//   P1: act2[2592]u4 (0..41471) | w2[1152]u4 (41472..59903)
//   P2: h2[1024]f   (0..4095)   | act3[1600]u4 (4096..29695)
//   P3: h3[512]f    (0..2047)
// ---------------------------------------------------------------------------
__global__ __launch_bounds__(512, 2) void kan_l2l3lin(
        const float* __restrict__ h1,
        const float* __restrict__ bw2, const float* __restrict__ sw2,
        const float* __restrict__ sc2,
        const uint4* __restrict__ w3g,
        const float* __restrict__ lin_w, const float* __restrict__ lin_b,
        float* __restrict__ out) {
    constexpr int NT = 512;
    __shared__ alignas(16) unsigned char s_mem[59904];
    uint4* s_act2 = (uint4*)s_mem;                 // [2592]
    uint4* s_w2   = (uint4*)(s_mem + 41472);       // [1152]
    float* s_h2   = (float*)s_mem;                 // [1024]
    uint4* s_act3 = (uint4*)(s_mem + 4096);        // [1600]
    float* s_h3   = (float*)s_mem;                 // [512]

    const int tid = threadIdx.x;
    const int n   = blockIdx.x;
    const int lane = tid & 63;
    const int wv   = tid >> 6;
    const int kg   = lane >> 4;
    const int oc   = lane & 15;
    const int m    = lane & 15;

    const uint4 zrec = act_record(0.0f);

    // ---- P1 stage: w2 fused [fp][16] + act2 zrec prefill
    for (int i = tid; i < 72 * 16; i += NT) {
        int fp = i >> 4, o = i & 15;
        s_w2[i] = fuse_w(bw2, sw2, sc2, o * 72 + fp);
    }
    for (int i = tid; i < 2592; i += NT) s_act2[i] = zrec;
    __syncthreads();
    // ---- P1 stage: act2 interior (8ch x 16 x 16, contiguous float4 loads)
    {
        const float4* xb4 = (const float4*)(h1 + (size_t)n * 8 * 16 * 16);
        float4 v4 = xb4[tid];                      // 2048 floats = 512 float4
        int cc   = tid >> 6;
        int rr_i = (tid >> 2) & 15;
        int c4   = (tid & 3) * 4;
        uint4* dst = &s_act2[(cc * 18 + rr_i + 1) * 18 + c4 + 1];
        dst[0] = act_record(v4.x);
        dst[1] = act_record(v4.y);
        dst[2] = act_record(v4.z);
        dst[3] = act_record(v4.w);
    }
    __syncthreads();

    // ---- L2 MFMA (K split 9+9 for ILP): 2 row-tiles per wave
    {
        bf16x8 bfr2[18];
#pragma unroll
        for (int s = 0; s < 18; ++s)
            bfr2[s] = *reinterpret_cast<const bf16x8*>(&s_w2[(4 * s + kg) * 16 + oc]);
        const int p0 = (2 * wv) * 18 + m;
        const int p1 = p0 + 18;
        f32x4 a0 = (f32x4){0.f, 0.f, 0.f, 0.f}, a1 = a0, b0 = a0, b1 = a0;
#pragma unroll
        for (int s = 0; s < 18; ++s) {
            int tp = 4 * s + kg;
            int c  = tp / 9;
            int t9 = tp - 9 * c;
            int ky = t9 / 3;
            int kx = t9 - 3 * ky;
            int base = (c * 18 + ky) * 18 + kx;
            bf16x8 av0 = *reinterpret_cast<const bf16x8*>(&s_act2[base + p0]);
            bf16x8 av1 = *reinterpret_cast<const bf16x8*>(&s_act2[base + p1]);
            if (s < 9) {
                a0 = __builtin_amdgcn_mfma_f32_16x16x32_bf16(av0, bfr2[s], a0, 0, 0, 0);
                a1 = __builtin_amdgcn_mfma_f32_16x16x32_bf16(av1, bfr2[s], a1, 0, 0, 0);
            } else {
                b0 = __builtin_amdgcn_mfma_f32_16x16x32_bf16(av0, bfr2[s], b0, 0, 0, 0);
                b1 = __builtin_amdgcn_mfma_f32_16x16x32_bf16(av1, bfr2[s], b1, 0, 0, 0);
            }
        }
        a0 = a0 + b0;
        a1 = a1 + b1;
        float e0 = fmaxf(a0[0], a1[0]);
        float e1 = fmaxf(a0[1], a1[1]);
        float e2 = fmaxf(a0[2], a1[2]);
        float e3 = fmaxf(a0[3], a1[3]);
        __syncthreads();                           // act2/w2 reads done
        // pooled h2: ch=oc, prow=wv, pcols 2kg,2kg+1
        s_h2[(oc * 8 + wv) * 8 + 2 * kg]     = fmaxf(e0, e1);
        s_h2[(oc * 8 + wv) * 8 + 2 * kg + 1] = fmaxf(e2, e3);
    }
    __syncthreads();                               // h2 visible

    // ---- P2 stage: act3 zrec prefill, then interior (16ch x 8 x 8)
    for (int i = tid; i < 1600; i += NT) s_act3[i] = zrec;
    __syncthreads();
    for (int i = tid; i < 1024; i += NT) {
        float val = s_h2[i];
        int cc   = i >> 6;
        int rr_i = (i >> 3) & 7;
        int col_i = i & 7;
        s_act3[(cc * 10 + rr_i + 1) * 10 + col_i + 1] = act_record(val);
    }
    __syncthreads();

    // ---- L3 MFMA (K split 18+18): wave wv -> mt=wv&3, o-half 16*(wv>>2)
    {
        const int mt  = wv & 3;
        const int o03 = 16 * (wv >> 2);
        bf16x8 bfr3[36];
#pragma unroll
        for (int s = 0; s < 36; ++s)
            bfr3[s] = *reinterpret_cast<const bf16x8*>(&w3g[(4 * s + kg) * 32 + o03 + oc]);
        const int poff = (2 * mt + (m >> 3)) * 10 + (m & 7);
        f32x4 a3 = (f32x4){0.f, 0.f, 0.f, 0.f}, a3b = a3;
#pragma unroll
        for (int s = 0; s < 36; ++s) {
            int tp = 4 * s + kg;
            int c  = tp / 9;
            int t9 = tp - 9 * c;
            int ky = t9 / 3;
            int kx = t9 - 3 * ky;
            int base = (c * 10 + ky) * 10 + kx;
            bf16x8 av = *reinterpret_cast<const bf16x8*>(&s_act3[base + poff]);
            if (s < 18)
                a3 = __builtin_amdgcn_mfma_f32_16x16x32_bf16(av, bfr3[s], a3, 0, 0, 0);
            else
                a3b = __builtin_amdgcn_mfma_f32_16x16x32_bf16(av, bfr3[s], a3b, 0, 0, 0);
        }
        a3 = a3 + a3b;
        float q0 = fmaxf(a3[0], a3[1]);
        float q1 = fmaxf(a3[2], a3[3]);
        float y0 = fmaxf(q0, __shfl_xor(q0, 32));
        float y1 = fmaxf(q1, __shfl_xor(q1, 32));
        // h3 (bytes 0..2047) disjoint from act3 (4096+): no pre-sync needed
        if (kg < 2) {
            s_h3[(o03 + oc) * 16 + mt * 4 + 2 * kg]     = y0;
            s_h3[(o03 + oc) * 16 + mt * 4 + 2 * kg + 1] = y1;
        }
    }
    __syncthreads();

    // ---- linear: 2-deep pipelined w-row loads + shfl reduce
    {
        const float4* hf = (const float4*)s_h3;
        const float4 h0v = hf[lane];
        const float4 h1v = hf[lane + 64];
        const float4* wr = (const float4*)(lin_w + (size_t)wv * 512);
        float4 w0 = wr[lane];
        float4 w1 = wr[lane + 64];
#pragma unroll 1
        for (int o = wv; o < 100; o += 8) {
            float4 nw0, nw1;
            const int on = o + 8;
            if (on < 100) {
                const float4* wn = (const float4*)(lin_w + (size_t)on * 512);
                nw0 = wn[lane];
                nw1 = wn[lane + 64];
            }
            float p = w0.x * h0v.x + w0.y * h0v.y + w0.z * h0v.z + w0.w * h0v.w
                    + w1.x * h1v.x + w1.y * h1v.y + w1.z * h1v.z + w1.w * h1v.w;
            p += __shfl_xor(p, 32);
            p += __shfl_xor(p, 16);
            p += __shfl_xor(p, 8);
            p += __shfl_xor(p, 4);
            p += __shfl_xor(p, 2);
            p += __shfl_xor(p, 1);
            if (lane == 0) out[(size_t)n * 100 + o] = p + lin_b[o];
            w0 = nw0;
            w1 = nw1;
        }
    }
}

extern "C" void kernel_launch(void* const* d_in, const int* in_sizes, int n_in,
                              void* d_out, int out_size, void* d_ws, size_t ws_size,
                              hipStream_t stream) {
    const float* x     = (const float*)d_in[0];
    const float* c1_bw = (const float*)d_in[1];
    const float* c1_sw = (const float*)d_in[2];
    const float* c1_sc = (const float*)d_in[3];
    const float* c2_bw = (const float*)d_in[4];
    const float* c2_sw = (const float*)d_in[5];
    const float* c2_sc = (const float*)d_in[6];
    const float* c3_bw = (const float*)d_in[7];
    const float* c3_sw = (const float*)d_in[8];
    const float* c3_sc = (const float*)d_in[9];
    const float* lin_w = (const float*)d_in[10];
    const float* lin_b = (const float*)d_in[11];
    float* out = (float*)d_out;

    float* ws = (float*)d_ws;
    float* h1 = ws;                      // 256*8*16*16 = 524288 floats
    uint4* w3g = (uint4*)(h1 + 524288);  // 4608 records = 73728 B

    // Kernel A: L1 [256,3,32,32] -> h1 [256,8,16,16]; + w3g prep (blocks 0-8).
    kan_l1<<<512, 512, 0, stream>>>(x, c1_bw, c1_sw, c1_sc,
                                    c3_bw, c3_sw, c3_sc, w3g, h1);
    // Kernel B: per-image L2 -> L3 -> linear. 256 blocks x 512.
    kan_l2l3lin<<<256, 512, 0, stream>>>(h1, c2_bw, c2_sw, c2_sc,
                                         w3g, lin_w, lin_b, out);
}